// Round 3
// baseline (298.056 us; speedup 1.0000x reference)
//
#include <hip/hip_runtime.h>

#define KNN 20
#define EPSBN 1e-5f

__device__ __forceinline__ float lrelu(float z) { return fmaxf(z, 0.2f * z); }

__device__ __forceinline__ int mbcnt64(unsigned long long m) {
  return __builtin_amdgcn_mbcnt_hi((unsigned)(m >> 32),
                                   __builtin_amdgcn_mbcnt_lo((unsigned)m, 0));
}

// Full-wave (64-lane) float sum via DPP (VALU pipe, no LDS). Result broadcast to all lanes.
__device__ __forceinline__ float wave64_sum(float x) {
#define DPP_ADD(ctrl)                                                                   \
  {                                                                                     \
    int _t = __builtin_amdgcn_update_dpp(0, __float_as_int(x), (ctrl), 0xF, 0xF, true); \
    x += __int_as_float(_t);                                                            \
  }
  DPP_ADD(0x111)  // row_shr:1
  DPP_ADD(0x112)  // row_shr:2
  DPP_ADD(0x114)  // row_shr:4
  DPP_ADD(0x118)  // row_shr:8
  DPP_ADD(0x142)  // row_bcast15
  DPP_ADD(0x143)  // row_bcast31 -> lane63 = total
#undef DPP_ADD
  return __int_as_float(__builtin_amdgcn_readlane(__float_as_int(x), 63));
}

// ---------------- K0: pack points as (x,y,z,||x||^2) ----------------
__global__ __launch_bounds__(256) void prep_kernel(const float* __restrict__ x,
                                                   float4* __restrict__ xq) {
  const int t = blockIdx.x * 256 + threadIdx.x;  // t = b*1024 + n
  const int b = t >> 10, n = t & 1023;
  const float* xb = x + b * 3072;
  const float x0 = xb[n], x1 = xb[1024 + n], x2 = xb[2048 + n];
  float4 p;
  p.x = x0; p.y = x1; p.z = x2;
  p.w = x0 * x0 + x1 * x1 + x2 * x2;
  xq[t] = p;
}

// ---------------- K1: kNN top-20 SET via radix bisection (one wave per point) ----------------
// Downstream softmax+weighted-sum is permutation-invariant in k, so only the top-20
// SET matters. Key: u ascending == pd descending; ties resolved in j order == top_k's
// lowest-index tie-break. pd formula bit-identical to the passing round-2 kernel.
__global__ __launch_bounds__(256) void knn_kernel(const float4* __restrict__ xq,
                                                  int* __restrict__ idx_out) {
  const int lane = threadIdx.x & 63;
  const int point = blockIdx.x * 4 + (threadIdx.x >> 6);
  const int b = point >> 10;
  const int iself = point & 1023;
  const float4* xb = xq + (b << 10);
  const float4 ci = xq[point];

  unsigned u[16];
#pragma unroll
  for (int r = 0; r < 16; ++r) {
    const int j = (r << 6) + lane;               // coalesced dwordx4 across lanes
    const float4 p = xb[j];
    const float dot = ci.x * p.x + ci.y * p.y + ci.z * p.z;
    const float pd = 2.0f * dot - ci.w - p.w;    // = -||xi-xj||^2 (same formula as R2)
    // pd <= 0 for all j != i (distinct points); self pd == +0.0 exactly.
    const unsigned ub = __float_as_uint(pd) ^ 0x80000000u;  // descending pd -> ascending u
    u[r] = (j == iself) ? 0u : ub;               // self is rank-0 (pd = 0 is the max)
  }

  // T = 20th-smallest u = max{t : #(u < t) <= 19}, built MSB->LSB. Wave-uniform.
  unsigned T = 0u;
  for (int bit = 31; bit >= 0; --bit) {
    const unsigned cand = T | (1u << bit);
    int cnt = 0;
#pragma unroll
    for (int r = 0; r < 16; ++r) cnt += __popcll(__ballot(u[r] < cand));  // v_cmp + s_bcnt1
    if (cnt <= 19) T = cand;
  }

  int* op = idx_out + point * KNN;
  // Pass 1: all strictly-above-threshold neighbors (u < T) -> ranks [0, base)
  int base = 0;
#pragma unroll
  for (int r = 0; r < 16; ++r) {
    const bool sel = (u[r] < T);
    const unsigned long long m = __ballot(sel);
    const int pos = base + mbcnt64(m);
    if (sel) op[pos] = (r << 6) + lane;
    base += __popcll(m);                          // wave-uniform (SGPR)
  }
  // Pass 2: fill remaining slots with u == T in j order (lowest index first).
  for (int r = 0; r < 16 && base < KNN; ++r) {
    const bool sel = (u[r] == T);
    const unsigned long long m = __ballot(sel);
    const int pos = base + mbcnt64(m);
    if (sel && pos < KNN) op[pos] = (r << 6) + lane;
    base += __popcll(m);
  }
}

// ---------------- K2: LAB attention (one wave per point, lane = channel) ----------------
__global__ __launch_bounds__(256) void lab_kernel(const float4* __restrict__ xq,
                                                  const int* __restrict__ idx,
                                                  const float* __restrict__ Wk,
                                                  const float* __restrict__ Wv,
                                                  const float* __restrict__ Ws,
                                                  const float* __restrict__ bnk,
                                                  const float* __restrict__ bnv,
                                                  const float* __restrict__ bns,
                                                  float* __restrict__ agg_out) {
  const int lane = threadIdx.x & 63;
  int point = (blockIdx.x << 2) + (threadIdx.x >> 6);
  point = __builtin_amdgcn_readfirstlane(point);  // wave-uniform -> scalar loads
  const int b = point >> 10;
  const int c = lane;

  // Fold eval-mode BN into weights: bn(z) = z*scale + shift
  const float sk = bnk[c] / sqrtf(bnk[192 + c] + EPSBN);
  const float hk = bnk[64 + c] - bnk[128 + c] * sk;
  const float sv = bnv[c] / sqrtf(bnv[192 + c] + EPSBN);
  const float hv = bnv[64 + c] - bnv[128 + c] * sv;
  const float ss = bns[0] / sqrtf(bns[3] + EPSBN);
  const float hs = bns[1] - bns[2] * ss;

  float wv[10];
#pragma unroll
  for (int f = 0; f < 10; ++f) wv[f] = Wv[c * 10 + f] * sv;
  const float wss = Ws[c] * ss;
  const float wk0 = Wk[c * 3 + 0] * sk, wk1 = Wk[c * 3 + 1] * sk, wk2 = Wk[c * 3 + 2] * sk;

  const float4 ctr = xq[point];
  const float q = lrelu(wk0 * ctr.x + wk1 * ctr.y + wk2 * ctr.z + hk);

  const int* ip = idx + point * KNN;
  float v[KNN], s[KNN];
#pragma unroll
  for (int k = 0; k < KNN; ++k) {
    const int j = ip[k];
    const float4 nb = xq[(b << 10) + j];
    const float d0 = nb.x - ctr.x, d1 = nb.y - ctr.y, d2 = nb.z - ctr.z;
    const float ded = d0 * d0 + d1 * d1 + d2 * d2;
    const float z = wv[0] * ded + wv[1] * d0 + wv[2] * d1 + wv[3] * d2 + wv[4] * ctr.x +
                    wv[5] * ctr.y + wv[6] * ctr.z + wv[7] * nb.x + wv[8] * nb.y +
                    wv[9] * nb.z + hv;
    const float vk = lrelu(z);
    v[k] = vk;
    s[k] = lrelu(wave64_sum(wss * (q + vk)) + hs);  // Sigma_c Ws_c*(q+v), BN folded
  }
  // softmax over k (wave-uniform values)
  float m = s[0];
#pragma unroll
  for (int k = 1; k < KNN; ++k) m = fmaxf(m, s[k]);
  float e[KNN];
  float den = 0.f;
#pragma unroll
  for (int k = 0; k < KNN; ++k) {
    e[k] = __expf(s[k] - m);
    den += e[k];
  }
  const float inv = 1.0f / den;
  float agg = 0.f;
#pragma unroll
  for (int k = 0; k < KNN; ++k) agg = fmaf(v[k], e[k] * inv, agg);
  agg_out[(point << 6) + c] = agg;  // [point][c] -> coalesced
}

// ---------------- K3: conv2 (64x64) + BN + ReLU (thread per point, W2 via SMEM) ----------------
__global__ __launch_bounds__(256) void conv2_kernel(const float* __restrict__ agg,
                                                    const float* __restrict__ W2,
                                                    const float* __restrict__ b2,
                                                    const float* __restrict__ bnc2,
                                                    float* __restrict__ out) {
  const int t = blockIdx.x * 256 + threadIdx.x;  // t = b*1024 + n
  const float4* a4 = (const float4*)(agg + (t << 6));
  float acc[64];
#pragma unroll
  for (int o = 0; o < 64; ++o) acc[o] = 0.f;
#pragma unroll
  for (int cq = 0; cq < 16; ++cq) {
    const float4 a = a4[cq];
#pragma unroll
    for (int o = 0; o < 64; ++o) {
      const float* w = W2 + (o << 6) + (cq << 2);  // threadIdx-independent -> s_load
      acc[o] = fmaf(w[0], a.x, fmaf(w[1], a.y, fmaf(w[2], a.z, fmaf(w[3], a.w, acc[o]))));
    }
  }
  const int b = t >> 10, n = t & 1023;
  float* op = out + (b << 16) + n;
#pragma unroll
  for (int o = 0; o < 64; ++o) {
    const float sc = bnc2[o] / sqrtf(bnc2[192 + o] + EPSBN);
    const float z = acc[o] + b2[o];
    op[o << 10] = fmaxf(fmaf(z - bnc2[128 + o], sc, bnc2[64 + o]), 0.f);
  }
}

extern "C" void kernel_launch(void* const* d_in, const int* in_sizes, int n_in,
                              void* d_out, int out_size, void* d_ws, size_t ws_size,
                              hipStream_t stream) {
  const float* x    = (const float*)d_in[0];
  const float* Wk   = (const float*)d_in[1];
  const float* Wv   = (const float*)d_in[2];
  const float* Ws   = (const float*)d_in[3];
  const float* W2   = (const float*)d_in[4];
  const float* b2   = (const float*)d_in[5];
  const float* bnk  = (const float*)d_in[6];
  const float* bnv  = (const float*)d_in[7];
  const float* bns  = (const float*)d_in[8];
  const float* bnc2 = (const float*)d_in[9];

  // ws layout: xq (1 MB) | idx (5 MB) | agg (16 MB)
  float4* xq = (float4*)d_ws;
  int* idx   = (int*)((char*)d_ws + (1 << 20));
  float* agg = (float*)((char*)d_ws + 6291456);
  float* out = (float*)d_out;

  prep_kernel<<<256, 256, 0, stream>>>(x, xq);
  knn_kernel<<<16384, 256, 0, stream>>>(xq, idx);
  lab_kernel<<<16384, 256, 0, stream>>>(xq, idx, Wk, Wv, Ws, bnk, bnv, bns, agg);
  conv2_kernel<<<256, 256, 0, stream>>>(agg, W2, b2, bnc2, out);
}

// Round 4
// 239.920 us; speedup vs baseline: 1.2423x; 1.2423x over previous
//
#include <hip/hip_runtime.h>

#define KNN 20
#define EPSBN 1e-5f

__device__ __forceinline__ float lrelu(float z) { return fmaxf(z, 0.2f * z); }

__device__ __forceinline__ int mbcnt64(unsigned long long m) {
  return __builtin_amdgcn_mbcnt_hi((unsigned)(m >> 32),
                                   __builtin_amdgcn_mbcnt_lo((unsigned)m, 0));
}

// Full-wave (64-lane) float sum via DPP (VALU pipe, no LDS). Result broadcast to all lanes.
__device__ __forceinline__ float wave64_sum(float x) {
#define DPP_ADD(ctrl)                                                                   \
  {                                                                                     \
    int _t = __builtin_amdgcn_update_dpp(0, __float_as_int(x), (ctrl), 0xF, 0xF, true); \
    x += __int_as_float(_t);                                                            \
  }
  DPP_ADD(0x111)  // row_shr:1
  DPP_ADD(0x112)  // row_shr:2
  DPP_ADD(0x114)  // row_shr:4
  DPP_ADD(0x118)  // row_shr:8
  DPP_ADD(0x142)  // row_bcast15
  DPP_ADD(0x143)  // row_bcast31 -> lane63 = total
#undef DPP_ADD
  return __int_as_float(__builtin_amdgcn_readlane(__float_as_int(x), 63));
}

// Full-wave uint min, result read from lane 63. bound_ctrl=false + old=self so
// invalid source lanes contribute min(x,x)=x. Same DPP ladder as the proven wave64_max.
__device__ __forceinline__ unsigned wave64_min_u32(unsigned x) {
#define DPP_MIN(ctrl)                                                       \
  {                                                                         \
    int _t = __builtin_amdgcn_update_dpp((int)x, (int)x, (ctrl), 0xF, 0xF, false); \
    x = min(x, (unsigned)_t);                                               \
  }
  DPP_MIN(0x111) DPP_MIN(0x112) DPP_MIN(0x114) DPP_MIN(0x118)
  DPP_MIN(0x142) DPP_MIN(0x143)
#undef DPP_MIN
  return (unsigned)__builtin_amdgcn_readlane((int)x, 63);
}

// ---------------- K0: pack points as (x,y,z,||x||^2) ----------------
__global__ __launch_bounds__(256) void prep_kernel(const float* __restrict__ x,
                                                   float4* __restrict__ xq) {
  const int t = blockIdx.x * 256 + threadIdx.x;  // t = b*1024 + n
  const int b = t >> 10, n = t & 1023;
  const float* xb = x + b * 3072;
  const float x0 = xb[n], x1 = xb[1024 + n], x2 = xb[2048 + n];
  float4 p;
  p.x = x0; p.y = x1; p.z = x2;
  p.w = x0 * x0 + x1 * x1 + x2 * x2;
  xq[t] = p;
}

// ---------------- K1: kNN top-20 SET (one wave per point, keys-only tournament) ----------------
// Downstream softmax+weighted-sum is permutation-invariant in k, so only the top-20
// SET matters. Plan: (a) exact sortable uint keys (R3's proven mapping, untouched copy
// u0), (b) per-lane bitonic sort of keys ONLY (v_min/v_max, 2 ops/cswap), (c) 20
// DPP-wave-min tournament rounds with single-register pops -> exact 20th-smallest key T,
// (d) R3's proven ballot-compaction collection on u0 vs T recovers indices in
// top_k-compatible order (ties by ascending j).
__global__ __launch_bounds__(256) void knn_kernel(const float4* __restrict__ xq,
                                                  int* __restrict__ idx_out) {
  const int lane = threadIdx.x & 63;
  const int point = blockIdx.x * 4 + (threadIdx.x >> 6);
  const int b = point >> 10;
  const int iself = point & 1023;
  const float4* xb = xq + (b << 10);
  const float4 ci = xq[point];

  unsigned u0[16], u[16];
#pragma unroll
  for (int r = 0; r < 16; ++r) {
    const int j = (r << 6) + lane;               // coalesced dwordx4 across lanes
    const float4 p = xb[j];
    const float dot = ci.x * p.x + ci.y * p.y + ci.z * p.z;
    const float pd = 2.0f * dot - ci.w - p.w;    // = -||xi-xj||^2 (bit-identical to R2/R3)
    const unsigned ub = __float_as_uint(pd) ^ 0x80000000u;  // ascending u == descending pd
    u0[r] = (j == iself) ? 0u : ub;              // self is rank-0 (pd = +0.0 is the max)
    u[r] = u0[r];
  }

  // Per-lane bitonic sort ascending, keys only -> v_min_u32/v_max_u32 pairs.
#pragma unroll
  for (int kk = 2; kk <= 16; kk <<= 1) {
#pragma unroll
    for (int jj = kk >> 1; jj > 0; jj >>= 1) {
#pragma unroll
      for (int i = 0; i < 16; ++i) {
        const int l = i ^ jj;
        if (l > i) {
          const unsigned lo = min(u[i], u[l]);
          const unsigned hi = max(u[i], u[l]);
          const bool up = ((i & kk) == 0);
          u[i] = up ? lo : hi;
          u[l] = up ? hi : lo;
        }
      }
    }
  }

  // 20 tournament rounds: wave-min of per-lane heads; winning lane pops (1-reg shift).
  // The 20th round's min is exactly T = 20th-smallest key.
  unsigned T = 0u;
#pragma unroll
  for (int r = 0; r < KNN; ++r) {
    T = wave64_min_u32(u[0]);
    if (r < KNN - 1) {
      const unsigned long long m = __ballot(u[0] == T);
      const int first = (int)__ffsll(m) - 1;
      if (lane == first) {
#pragma unroll
        for (int t = 0; t < 15; ++t) u[t] = u[t + 1];
        u[15] = 0xFFFFFFFFu;
      }
    }
  }

  int* op = idx_out + point * KNN;
  // Pass 1: strictly-above-threshold neighbors (u0 < T) -> ranks [0, base)
  int base = 0;
#pragma unroll
  for (int r = 0; r < 16; ++r) {
    const bool sel = (u0[r] < T);
    const unsigned long long m = __ballot(sel);
    const int pos = base + mbcnt64(m);
    if (sel) op[pos] = (r << 6) + lane;
    base += __popcll(m);                          // wave-uniform (SGPR)
  }
  // Pass 2: fill remaining slots with u0 == T in j order (lowest index first).
  for (int r = 0; r < 16 && base < KNN; ++r) {
    const bool sel = (u0[r] == T);
    const unsigned long long m = __ballot(sel);
    const int pos = base + mbcnt64(m);
    if (sel && pos < KNN) op[pos] = (r << 6) + lane;
    base += __popcll(m);
  }
}

// ---------------- K2: LAB attention (one wave per point, lane = channel) ----------------
__global__ __launch_bounds__(256) void lab_kernel(const float4* __restrict__ xq,
                                                  const int* __restrict__ idx,
                                                  const float* __restrict__ Wk,
                                                  const float* __restrict__ Wv,
                                                  const float* __restrict__ Ws,
                                                  const float* __restrict__ bnk,
                                                  const float* __restrict__ bnv,
                                                  const float* __restrict__ bns,
                                                  float* __restrict__ agg_out) {
  const int lane = threadIdx.x & 63;
  int point = (blockIdx.x << 2) + (threadIdx.x >> 6);
  point = __builtin_amdgcn_readfirstlane(point);  // wave-uniform -> scalar loads
  const int b = point >> 10;
  const int c = lane;

  // Fold eval-mode BN into weights: bn(z) = z*scale + shift
  const float sk = bnk[c] / sqrtf(bnk[192 + c] + EPSBN);
  const float hk = bnk[64 + c] - bnk[128 + c] * sk;
  const float sv = bnv[c] / sqrtf(bnv[192 + c] + EPSBN);
  const float hv = bnv[64 + c] - bnv[128 + c] * sv;
  const float ss = bns[0] / sqrtf(bns[3] + EPSBN);
  const float hs = bns[1] - bns[2] * ss;

  float wv[10];
#pragma unroll
  for (int f = 0; f < 10; ++f) wv[f] = Wv[c * 10 + f] * sv;
  const float wss = Ws[c] * ss;
  const float wk0 = Wk[c * 3 + 0] * sk, wk1 = Wk[c * 3 + 1] * sk, wk2 = Wk[c * 3 + 2] * sk;

  const float4 ctr = xq[point];
  const float q = lrelu(wk0 * ctr.x + wk1 * ctr.y + wk2 * ctr.z + hk);

  const int* ip = idx + point * KNN;
  float v[KNN], s[KNN];
#pragma unroll
  for (int k = 0; k < KNN; ++k) {
    const int j = ip[k];
    const float4 nb = xq[(b << 10) + j];
    const float d0 = nb.x - ctr.x, d1 = nb.y - ctr.y, d2 = nb.z - ctr.z;
    const float ded = d0 * d0 + d1 * d1 + d2 * d2;
    const float z = wv[0] * ded + wv[1] * d0 + wv[2] * d1 + wv[3] * d2 + wv[4] * ctr.x +
                    wv[5] * ctr.y + wv[6] * ctr.z + wv[7] * nb.x + wv[8] * nb.y +
                    wv[9] * nb.z + hv;
    const float vk = lrelu(z);
    v[k] = vk;
    s[k] = lrelu(wave64_sum(wss * (q + vk)) + hs);  // Sigma_c Ws_c*(q+v), BN folded
  }
  // softmax over k (wave-uniform values)
  float m = s[0];
#pragma unroll
  for (int k = 1; k < KNN; ++k) m = fmaxf(m, s[k]);
  float e[KNN];
  float den = 0.f;
#pragma unroll
  for (int k = 0; k < KNN; ++k) {
    e[k] = __expf(s[k] - m);
    den += e[k];
  }
  const float inv = 1.0f / den;
  float agg = 0.f;
#pragma unroll
  for (int k = 0; k < KNN; ++k) agg = fmaf(v[k], e[k] * inv, agg);
  agg_out[(point << 6) + c] = agg;  // [point][c] -> coalesced
}

// ---------------- K3: conv2 (64x64) + BN + ReLU (thread per point, W2 via SMEM) ----------------
__global__ __launch_bounds__(256) void conv2_kernel(const float* __restrict__ agg,
                                                    const float* __restrict__ W2,
                                                    const float* __restrict__ b2,
                                                    const float* __restrict__ bnc2,
                                                    float* __restrict__ out) {
  const int t = blockIdx.x * 256 + threadIdx.x;  // t = b*1024 + n
  const float4* a4 = (const float4*)(agg + (t << 6));
  float acc[64];
#pragma unroll
  for (int o = 0; o < 64; ++o) acc[o] = 0.f;
#pragma unroll
  for (int cq = 0; cq < 16; ++cq) {
    const float4 a = a4[cq];
#pragma unroll
    for (int o = 0; o < 64; ++o) {
      const float* w = W2 + (o << 6) + (cq << 2);  // threadIdx-independent -> s_load
      acc[o] = fmaf(w[0], a.x, fmaf(w[1], a.y, fmaf(w[2], a.z, fmaf(w[3], a.w, acc[o]))));
    }
  }
  const int b = t >> 10, n = t & 1023;
  float* op = out + (b << 16) + n;
#pragma unroll
  for (int o = 0; o < 64; ++o) {
    const float sc = bnc2[o] / sqrtf(bnc2[192 + o] + EPSBN);
    const float z = acc[o] + b2[o];
    op[o << 10] = fmaxf(fmaf(z - bnc2[128 + o], sc, bnc2[64 + o]), 0.f);
  }
}

extern "C" void kernel_launch(void* const* d_in, const int* in_sizes, int n_in,
                              void* d_out, int out_size, void* d_ws, size_t ws_size,
                              hipStream_t stream) {
  const float* x    = (const float*)d_in[0];
  const float* Wk   = (const float*)d_in[1];
  const float* Wv   = (const float*)d_in[2];
  const float* Ws   = (const float*)d_in[3];
  const float* W2   = (const float*)d_in[4];
  const float* b2   = (const float*)d_in[5];
  const float* bnk  = (const float*)d_in[6];
  const float* bnv  = (const float*)d_in[7];
  const float* bns  = (const float*)d_in[8];
  const float* bnc2 = (const float*)d_in[9];

  // ws layout: xq (1 MB) | idx (5 MB) | agg (16 MB)
  float4* xq = (float4*)d_ws;
  int* idx   = (int*)((char*)d_ws + (1 << 20));
  float* agg = (float*)((char*)d_ws + 6291456);
  float* out = (float*)d_out;

  prep_kernel<<<256, 256, 0, stream>>>(x, xq);
  knn_kernel<<<16384, 256, 0, stream>>>(xq, idx);
  lab_kernel<<<16384, 256, 0, stream>>>(xq, idx, Wk, Wv, Ws, bnk, bnv, bns, agg);
  conv2_kernel<<<256, 256, 0, stream>>>(agg, W2, b2, bnc2, out);
}

// Round 5
// 177.744 us; speedup vs baseline: 1.6769x; 1.3498x over previous
//
#include <hip/hip_runtime.h>

#define KNN 20
#define EPSBN 1e-5f

__device__ __forceinline__ float lrelu(float z) { return fmaxf(z, 0.2f * z); }

__device__ __forceinline__ int mbcnt64(unsigned long long m) {
  return __builtin_amdgcn_mbcnt_hi((unsigned)(m >> 32),
                                   __builtin_amdgcn_mbcnt_lo((unsigned)m, 0));
}

// Butterfly float sum across 64 lanes: 5 ds_swizzle + 1 ds_bpermute (LDS pipe)
// + 6 v_add (VALU). All lanes end with the total (per-lane rounding may differ
// by ulps -- harmless downstream).
__device__ __forceinline__ float xsum64(float x, int addr32) {
  x += __int_as_float(__builtin_amdgcn_ds_swizzle(__float_as_int(x), (1 << 10) | 0x1F));
  x += __int_as_float(__builtin_amdgcn_ds_swizzle(__float_as_int(x), (2 << 10) | 0x1F));
  x += __int_as_float(__builtin_amdgcn_ds_swizzle(__float_as_int(x), (4 << 10) | 0x1F));
  x += __int_as_float(__builtin_amdgcn_ds_swizzle(__float_as_int(x), (8 << 10) | 0x1F));
  x += __int_as_float(__builtin_amdgcn_ds_swizzle(__float_as_int(x), (16 << 10) | 0x1F));
  x += __int_as_float(__builtin_amdgcn_ds_bpermute(addr32, __float_as_int(x)));
  return x;
}

// One bitonic stage: exchange with lane^(1<<LJ), keep min/max per standard network.
// db[a] = (lane>>a)&1 precomputed; db[6] = 0 (so LK=6 block is the final ascending merge).
template <int LK, int LJ>
__device__ __forceinline__ void bstage(unsigned& x, const int* db, int addr32) {
  unsigned p;
  if constexpr (LJ == 5)
    p = (unsigned)__builtin_amdgcn_ds_bpermute(addr32, (int)x);
  else
    p = (unsigned)__builtin_amdgcn_ds_swizzle((int)x, ((1 << LJ) << 10) | 0x1F);
  const unsigned mn = min(x, p), mx = max(x, p);
  x = ((db[LK] ^ db[LJ]) == 0) ? mn : mx;  // keep min iff lane is "low" of an ascending pair
}

// Full cross-lane bitonic sort of 64 values (one per lane), ascending by lane.
__device__ __forceinline__ unsigned bsort64(unsigned x, const int* db, int addr32) {
  bstage<1, 0>(x, db, addr32);
  bstage<2, 1>(x, db, addr32); bstage<2, 0>(x, db, addr32);
  bstage<3, 2>(x, db, addr32); bstage<3, 1>(x, db, addr32); bstage<3, 0>(x, db, addr32);
  bstage<4, 3>(x, db, addr32); bstage<4, 2>(x, db, addr32); bstage<4, 1>(x, db, addr32);
  bstage<4, 0>(x, db, addr32);
  bstage<5, 4>(x, db, addr32); bstage<5, 3>(x, db, addr32); bstage<5, 2>(x, db, addr32);
  bstage<5, 1>(x, db, addr32); bstage<5, 0>(x, db, addr32);
  bstage<6, 5>(x, db, addr32); bstage<6, 4>(x, db, addr32); bstage<6, 3>(x, db, addr32);
  bstage<6, 2>(x, db, addr32); bstage<6, 1>(x, db, addr32); bstage<6, 0>(x, db, addr32);
  return x;
}

// ---------------- K0: pack points + fold BN weights (block 256) ----------------
__global__ __launch_bounds__(256) void prep_kernel(const float* __restrict__ x,
                                                   float4* __restrict__ xq,
                                                   const float* __restrict__ Wk,
                                                   const float* __restrict__ Wv,
                                                   const float* __restrict__ Ws,
                                                   const float* __restrict__ bnk,
                                                   const float* __restrict__ bnv,
                                                   const float* __restrict__ bns,
                                                   float* __restrict__ wf) {
  if (blockIdx.x == 256) {
    const int c = threadIdx.x;
    if (c < 64) {
      // identical expressions to the proven per-wave folding (bit-compatible)
      const float sk = bnk[c] / sqrtf(bnk[192 + c] + EPSBN);
      const float hk = bnk[64 + c] - bnk[128 + c] * sk;
      const float sv = bnv[c] / sqrtf(bnv[192 + c] + EPSBN);
      const float hv = bnv[64 + c] - bnv[128 + c] * sv;
      const float ss = bns[0] / sqrtf(bns[3] + EPSBN);
      float* r = wf + (c << 4);
      r[0] = Wk[c * 3 + 0] * sk; r[1] = Wk[c * 3 + 1] * sk; r[2] = Wk[c * 3 + 2] * sk;
      r[3] = hk;
#pragma unroll
      for (int f = 0; f < 10; ++f) r[4 + f] = Wv[c * 10 + f] * sv;
      r[14] = hv;
      r[15] = Ws[c] * ss;
      if (c == 0) wf[1024] = bns[1] - bns[2] * ss;  // hs
    }
    return;
  }
  const int t = blockIdx.x * 256 + threadIdx.x;  // t = b*1024 + n
  const int b = t >> 10, n = t & 1023;
  const float* xb = x + b * 3072;
  const float x0 = xb[n], x1 = xb[1024 + n], x2 = xb[2048 + n];
  float4 p;
  p.x = x0; p.y = x1; p.z = x2;
  p.w = x0 * x0 + x1 * x1 + x2 * x2;
  xq[t] = p;
}

// ---------------- K1: kNN top-20 SET, pop-free (one wave per point) ----------------
// T (exact 20th-smallest key) via: lane-mins -> bitonic-sort-64 -> tau = 20th-smallest
// lane-min (>= T, with >= 20 elements <= tau); compact survivors (u<=tau, expected ~29)
// into 64 LDS slots; bitonic-sort-64 -> T at lane 19. Wave-uniform fallback to the
// proven bisection if survivors > 64 (probability ~1e-8/point). Collection = R4's
// proven ballot-compaction passes on untouched u (top_k tie semantics preserved).
__global__ __launch_bounds__(256) void knn_kernel(const float4* __restrict__ xq,
                                                  int* __restrict__ idx_out) {
  __shared__ unsigned comp[4][64];
  const int lane = threadIdx.x & 63;
  const int w = threadIdx.x >> 6;
  const int point = blockIdx.x * 4 + w;
  const int b = point >> 10;
  const int iself = point & 1023;
  const float4* xb = xq + (b << 10);
  const float4 ci = xq[point];

  unsigned u[16];
#pragma unroll
  for (int r = 0; r < 16; ++r) {
    const int j = (r << 6) + lane;               // coalesced dwordx4 across lanes
    const float4 p = xb[j];
    const float dot = ci.x * p.x + ci.y * p.y + ci.z * p.z;
    const float pd = 2.0f * dot - ci.w - p.w;    // = -||xi-xj||^2 (bit-identical to R2-R4)
    const unsigned ub = __float_as_uint(pd) ^ 0x80000000u;  // ascending u == descending pd
    u[r] = (j == iself) ? 0u : ub;               // self is rank-0 (pd = +0.0 is the max)
  }

  int db[7];
#pragma unroll
  for (int a = 0; a < 6; ++a) db[a] = (lane >> a) & 1;
  db[6] = 0;
  const int addr32 = (lane ^ 32) << 2;

  // Per-lane min (unsorted keys, 15 v_min)
  unsigned lm = u[0];
#pragma unroll
  for (int r = 1; r < 16; ++r) lm = min(lm, u[r]);

  // tau = 20th-smallest lane-min (wave-uniform upper bound on T)
  const unsigned sm = bsort64(lm, db, addr32);
  const unsigned tau = (unsigned)__builtin_amdgcn_readlane((int)sm, 19);

  // Compact survivor VALUES (u <= tau) into this wave's 64 LDS slots.
  unsigned* cw = comp[w];
  cw[lane] = 0xFFFFFFFFu;
  __syncthreads();
  int base = 0;
#pragma unroll
  for (int r = 0; r < 16; ++r) {
    const bool sel = (u[r] <= tau);
    const unsigned long long m = __ballot(sel);
    const int pos = base + mbcnt64(m);
    if (sel && pos < 64) cw[pos] = u[r];
    base += __popcll(m);
  }
  __syncthreads();
  unsigned sv = cw[lane];

  unsigned T;
  if (base <= 64) {                              // always, in practice
    sv = bsort64(sv, db, addr32);
    T = (unsigned)__builtin_amdgcn_readlane((int)sv, 19);  // exact global 20th-smallest
  } else {
    // Fallback: proven radix bisection (R3). Keys < 2^31 -> 31 rounds.
    T = 0u;
    for (int bit = 30; bit >= 0; --bit) {
      const unsigned cand = T | (1u << bit);
      int cnt = 0;
#pragma unroll
      for (int r = 0; r < 16; ++r) cnt += __popcll(__ballot(u[r] < cand));
      if (cnt <= 19) T = cand;
    }
  }

  int* op = idx_out + point * KNN;
  // Pass 1: strictly-above-threshold neighbors (u < T) -> ranks [0, nbase)
  int nbase = 0;
#pragma unroll
  for (int r = 0; r < 16; ++r) {
    const bool sel = (u[r] < T);
    const unsigned long long m = __ballot(sel);
    const int pos = nbase + mbcnt64(m);
    if (sel) op[pos] = (r << 6) + lane;
    nbase += __popcll(m);
  }
  // Pass 2: fill remaining slots with u == T in j order (lowest index first).
  for (int r = 0; r < 16 && nbase < KNN; ++r) {
    const bool sel = (u[r] == T);
    const unsigned long long m = __ballot(sel);
    const int pos = nbase + mbcnt64(m);
    if (sel && pos < KNN) op[pos] = (r << 6) + lane;
    nbase += __popcll(m);
  }
}

// ---------------- K2: LAB attention (one wave per point, lane = channel) ----------------
__global__ __launch_bounds__(256) void lab_kernel(const float4* __restrict__ xq,
                                                  const int* __restrict__ idx,
                                                  const float* __restrict__ wf,
                                                  float* __restrict__ agg_out) {
  const int lane = threadIdx.x & 63;
  int point = (blockIdx.x << 2) + (threadIdx.x >> 6);
  point = __builtin_amdgcn_readfirstlane(point);  // wave-uniform -> scalar loads
  const int b = point >> 10;
  const int c = lane;
  const int addr32 = (lane ^ 32) << 2;

  // Pre-folded weights: {wk0,wk1,wk2,hk | wv0..3 | wv4..7 | wv8,wv9,hv,wss}
  const float4* wfc = (const float4*)(wf + (c << 4));
  const float4 w0 = wfc[0], w1 = wfc[1], w2 = wfc[2], w3 = wfc[3];
  const float hs = wf[1024];                      // uniform -> s_load

  const float4 ctr = xq[point];
  const float q = lrelu(fmaf(w0.x, ctr.x, fmaf(w0.y, ctr.y, fmaf(w0.z, ctr.z, w0.w))));
  // k-invariant part of z: wv4*cx + wv5*cy + wv6*cz + hv
  const float cterm = fmaf(w2.x, ctr.x, fmaf(w2.y, ctr.y, fmaf(w2.z, ctr.z, w3.z)));

  const int* ip = idx + point * KNN;
  float v[KNN], s[KNN];
  float m = -INFINITY;
#pragma unroll
  for (int k = 0; k < KNN; ++k) {
    const int j = ip[k];
    const float4 nb = xq[(b << 10) + j];
    const float d0 = nb.x - ctr.x, d1 = nb.y - ctr.y, d2 = nb.z - ctr.z;
    const float ded = fmaf(d0, d0, fmaf(d1, d1, d2 * d2));
    const float z = fmaf(w1.x, ded, fmaf(w1.y, d0, fmaf(w1.z, d1, fmaf(w1.w, d2,
                    fmaf(w2.w, nb.x, fmaf(w3.x, nb.y, fmaf(w3.y, nb.z, cterm)))))));
    const float vk = lrelu(z);
    v[k] = vk;
    const float sk = lrelu(xsum64(w3.w * (q + vk), addr32) + hs);
    s[k] = sk;
    m = fmaxf(m, sk);
  }
  // softmax over k; unnormalized accumulate, single divide at the end
  const float nm = -m * 1.44269504f;
  float den = 0.f, agg = 0.f;
#pragma unroll
  for (int k = 0; k < KNN; ++k) {
    const float e = exp2f(fmaf(s[k], 1.44269504f, nm));
    den += e;
    agg = fmaf(v[k], e, agg);
  }
  agg_out[(point << 6) + c] = agg * (1.0f / den);  // [point][c] -> coalesced
}

// ---------------- K3: conv2 (64x64) + BN + ReLU (thread per point, W2 via SMEM) ----------------
__global__ __launch_bounds__(256) void conv2_kernel(const float* __restrict__ agg,
                                                    const float* __restrict__ W2,
                                                    const float* __restrict__ b2,
                                                    const float* __restrict__ bnc2,
                                                    float* __restrict__ out) {
  const int t = blockIdx.x * 256 + threadIdx.x;  // t = b*1024 + n
  const float4* a4 = (const float4*)(agg + (t << 6));
  float acc[64];
#pragma unroll
  for (int o = 0; o < 64; ++o) acc[o] = 0.f;
#pragma unroll
  for (int cq = 0; cq < 16; ++cq) {
    const float4 a = a4[cq];
#pragma unroll
    for (int o = 0; o < 64; ++o) {
      const float* w = W2 + (o << 6) + (cq << 2);  // threadIdx-independent -> s_load
      acc[o] = fmaf(w[0], a.x, fmaf(w[1], a.y, fmaf(w[2], a.z, fmaf(w[3], a.w, acc[o]))));
    }
  }
  const int b = t >> 10, n = t & 1023;
  float* op = out + (b << 16) + n;
#pragma unroll
  for (int o = 0; o < 64; ++o) {
    const float sc = bnc2[o] / sqrtf(bnc2[192 + o] + EPSBN);
    const float z = acc[o] + b2[o];
    op[o << 10] = fmaxf(fmaf(z - bnc2[128 + o], sc, bnc2[64 + o]), 0.f);
  }
}

extern "C" void kernel_launch(void* const* d_in, const int* in_sizes, int n_in,
                              void* d_out, int out_size, void* d_ws, size_t ws_size,
                              hipStream_t stream) {
  const float* x    = (const float*)d_in[0];
  const float* Wk   = (const float*)d_in[1];
  const float* Wv   = (const float*)d_in[2];
  const float* Ws   = (const float*)d_in[3];
  const float* W2   = (const float*)d_in[4];
  const float* b2   = (const float*)d_in[5];
  const float* bnk  = (const float*)d_in[6];
  const float* bnv  = (const float*)d_in[7];
  const float* bns  = (const float*)d_in[8];
  const float* bnc2 = (const float*)d_in[9];

  // ws layout: xq (1 MB) | idx (5 MB) | agg (16 MB)
  float4* xq = (float4*)d_ws;
  int* idx   = (int*)((char*)d_ws + (1 << 20));
  float* agg = (float*)((char*)d_ws + 6291456);
  float* out = (float*)d_out;
  // Folded-weight scratch (4.1 KB) lives at the START of d_out: lab reads it, then
  // conv2 overwrites every element of d_out (stream-serialized) -> race-free.
  float* wf = (float*)d_out;

  prep_kernel<<<257, 256, 0, stream>>>(x, xq, Wk, Wv, Ws, bnk, bnv, bns, wf);
  knn_kernel<<<16384, 256, 0, stream>>>(xq, idx);
  lab_kernel<<<16384, 256, 0, stream>>>(xq, idx, wf, agg);
  conv2_kernel<<<256, 256, 0, stream>>>(agg, W2, b2, bnc2, out);
}

// Round 6
// 177.461 us; speedup vs baseline: 1.6796x; 1.0016x over previous
//
#include <hip/hip_runtime.h>

#define KNN 20
#define EPSBN 1e-5f

__device__ __forceinline__ float lrelu(float z) { return fmaxf(z, 0.2f * z); }

__device__ __forceinline__ int mbcnt64(unsigned long long m) {
  return __builtin_amdgcn_mbcnt_hi((unsigned)(m >> 32),
                                   __builtin_amdgcn_mbcnt_lo((unsigned)m, 0));
}

// Full-wave (64-lane) float sum via DPP (VALU pipe, no LDS). Result broadcast via
// readlane -> SGPR. Proven in R2-R4 lab.
__device__ __forceinline__ float wave64_sum(float x) {
#define DPP_ADD(ctrl)                                                                   \
  {                                                                                     \
    int _t = __builtin_amdgcn_update_dpp(0, __float_as_int(x), (ctrl), 0xF, 0xF, true); \
    x += __int_as_float(_t);                                                            \
  }
  DPP_ADD(0x111)  // row_shr:1
  DPP_ADD(0x112)  // row_shr:2
  DPP_ADD(0x114)  // row_shr:4
  DPP_ADD(0x118)  // row_shr:8
  DPP_ADD(0x142)  // row_bcast15
  DPP_ADD(0x143)  // row_bcast31 -> lane63 = total
#undef DPP_ADD
  return __int_as_float(__builtin_amdgcn_readlane(__float_as_int(x), 63));
}

// One bitonic stage: exchange with lane^(1<<LJ), keep min/max per standard network.
// db[a] = (lane>>a)&1 precomputed; db[6] = 0 (so LK=6 block is the final ascending merge).
template <int LK, int LJ>
__device__ __forceinline__ void bstage(unsigned& x, const int* db, int addr32) {
  unsigned p;
  if constexpr (LJ == 5)
    p = (unsigned)__builtin_amdgcn_ds_bpermute(addr32, (int)x);
  else
    p = (unsigned)__builtin_amdgcn_ds_swizzle((int)x, ((1 << LJ) << 10) | 0x1F);
  const unsigned mn = min(x, p), mx = max(x, p);
  x = ((db[LK] ^ db[LJ]) == 0) ? mn : mx;  // keep min iff lane is "low" of an ascending pair
}

// Full cross-lane bitonic sort of 64 values (one per lane), ascending by lane.
__device__ __forceinline__ unsigned bsort64(unsigned x, const int* db, int addr32) {
  bstage<1, 0>(x, db, addr32);
  bstage<2, 1>(x, db, addr32); bstage<2, 0>(x, db, addr32);
  bstage<3, 2>(x, db, addr32); bstage<3, 1>(x, db, addr32); bstage<3, 0>(x, db, addr32);
  bstage<4, 3>(x, db, addr32); bstage<4, 2>(x, db, addr32); bstage<4, 1>(x, db, addr32);
  bstage<4, 0>(x, db, addr32);
  bstage<5, 4>(x, db, addr32); bstage<5, 3>(x, db, addr32); bstage<5, 2>(x, db, addr32);
  bstage<5, 1>(x, db, addr32); bstage<5, 0>(x, db, addr32);
  bstage<6, 5>(x, db, addr32); bstage<6, 4>(x, db, addr32); bstage<6, 3>(x, db, addr32);
  bstage<6, 2>(x, db, addr32); bstage<6, 1>(x, db, addr32); bstage<6, 0>(x, db, addr32);
  return x;
}

// ---------------- K0: pack points + fold BN weights (block 256) ----------------
__global__ __launch_bounds__(256) void prep_kernel(const float* __restrict__ x,
                                                   float4* __restrict__ xq,
                                                   const float* __restrict__ Wk,
                                                   const float* __restrict__ Wv,
                                                   const float* __restrict__ Ws,
                                                   const float* __restrict__ bnk,
                                                   const float* __restrict__ bnv,
                                                   const float* __restrict__ bns,
                                                   float* __restrict__ wf) {
  if (blockIdx.x == 256) {
    const int c = threadIdx.x;
    if (c < 64) {
      const float sk = bnk[c] / sqrtf(bnk[192 + c] + EPSBN);
      const float hk = bnk[64 + c] - bnk[128 + c] * sk;
      const float sv = bnv[c] / sqrtf(bnv[192 + c] + EPSBN);
      const float hv = bnv[64 + c] - bnv[128 + c] * sv;
      const float ss = bns[0] / sqrtf(bns[3] + EPSBN);
      float* r = wf + (c << 4);
      r[0] = Wk[c * 3 + 0] * sk; r[1] = Wk[c * 3 + 1] * sk; r[2] = Wk[c * 3 + 2] * sk;
      r[3] = hk;
#pragma unroll
      for (int f = 0; f < 10; ++f) r[4 + f] = Wv[c * 10 + f] * sv;
      r[14] = hv;
      r[15] = Ws[c] * ss;
      if (c == 0) wf[1024] = bns[1] - bns[2] * ss;  // hs
    }
    return;
  }
  const int t = blockIdx.x * 256 + threadIdx.x;  // t = b*1024 + n
  const int b = t >> 10, n = t & 1023;
  const float* xb = x + b * 3072;
  const float x0 = xb[n], x1 = xb[1024 + n], x2 = xb[2048 + n];
  float4 p;
  p.x = x0; p.y = x1; p.z = x2;
  p.w = x0 * x0 + x1 * x1 + x2 * x2;
  xq[t] = p;
}

// ---------------- K1: kNN top-20 SET, pop-free (one wave per point) ----------------
// Identical to the R5-proven kernel: tau from sorted lane-mins; compact survivors;
// second sort -> exact T; ballot-compaction collection (top_k tie semantics).
__global__ __launch_bounds__(256) void knn_kernel(const float4* __restrict__ xq,
                                                  int* __restrict__ idx_out) {
  __shared__ unsigned comp[4][64];
  const int lane = threadIdx.x & 63;
  const int w = threadIdx.x >> 6;
  const int point = blockIdx.x * 4 + w;
  const int b = point >> 10;
  const int iself = point & 1023;
  const float4* xb = xq + (b << 10);
  const float4 ci = xq[point];

  unsigned u[16];
#pragma unroll
  for (int r = 0; r < 16; ++r) {
    const int j = (r << 6) + lane;               // coalesced dwordx4 across lanes
    const float4 p = xb[j];
    const float dot = ci.x * p.x + ci.y * p.y + ci.z * p.z;
    const float pd = 2.0f * dot - ci.w - p.w;    // = -||xi-xj||^2 (bit-identical to R2-R5)
    const unsigned ub = __float_as_uint(pd) ^ 0x80000000u;  // ascending u == descending pd
    u[r] = (j == iself) ? 0u : ub;               // self is rank-0 (pd = +0.0 is the max)
  }

  int db[7];
#pragma unroll
  for (int a = 0; a < 6; ++a) db[a] = (lane >> a) & 1;
  db[6] = 0;
  const int addr32 = (lane ^ 32) << 2;

  unsigned lm = u[0];
#pragma unroll
  for (int r = 1; r < 16; ++r) lm = min(lm, u[r]);

  const unsigned sm = bsort64(lm, db, addr32);
  const unsigned tau = (unsigned)__builtin_amdgcn_readlane((int)sm, 19);

  unsigned* cw = comp[w];
  cw[lane] = 0xFFFFFFFFu;
  __syncthreads();
  int base = 0;
#pragma unroll
  for (int r = 0; r < 16; ++r) {
    const bool sel = (u[r] <= tau);
    const unsigned long long m = __ballot(sel);
    const int pos = base + mbcnt64(m);
    if (sel && pos < 64) cw[pos] = u[r];
    base += __popcll(m);
  }
  __syncthreads();
  unsigned sv = cw[lane];

  unsigned T;
  if (base <= 64) {                              // always, in practice
    sv = bsort64(sv, db, addr32);
    T = (unsigned)__builtin_amdgcn_readlane((int)sv, 19);  // exact global 20th-smallest
  } else {
    T = 0u;                                      // proven R3 bisection fallback
    for (int bit = 30; bit >= 0; --bit) {
      const unsigned cand = T | (1u << bit);
      int cnt = 0;
#pragma unroll
      for (int r = 0; r < 16; ++r) cnt += __popcll(__ballot(u[r] < cand));
      if (cnt <= 19) T = cand;
    }
  }

  int* op = idx_out + point * KNN;
  int nbase = 0;
#pragma unroll
  for (int r = 0; r < 16; ++r) {
    const bool sel = (u[r] < T);
    const unsigned long long m = __ballot(sel);
    const int pos = nbase + mbcnt64(m);
    if (sel) op[pos] = (r << 6) + lane;
    nbase += __popcll(m);
  }
  for (int r = 0; r < 16 && nbase < KNN; ++r) {
    const bool sel = (u[r] == T);
    const unsigned long long m = __ballot(sel);
    const int pos = nbase + mbcnt64(m);
    if (sel && pos < KNN) op[pos] = (r << 6) + lane;
    nbase += __popcll(m);
  }
}

// ---------------- K2: LAB attention (one wave per point, lane = channel) ----------------
// Phase-split: prefetch idx -> compute all v[k] -> 20 independent DPP reductions ->
// softmax+agg. No LDS on the critical path; 20 reduction chains interleave.
__global__ __launch_bounds__(256) void lab_kernel(const float4* __restrict__ xq,
                                                  const int* __restrict__ idx,
                                                  const float* __restrict__ wf,
                                                  float* __restrict__ agg_out) {
  const int lane = threadIdx.x & 63;
  int point = (blockIdx.x << 2) + (threadIdx.x >> 6);
  point = __builtin_amdgcn_readfirstlane(point);  // wave-uniform -> scalar loads
  const int b = point >> 10;
  const int c = lane;

  // Pre-folded weights: {wk0,wk1,wk2,hk | wv0..3 | wv4..7 | wv8,wv9,hv,wss}
  const float4* wfc = (const float4*)(wf + (c << 4));
  const float4 w0 = wfc[0], w1 = wfc[1], w2 = wfc[2], w3 = wfc[3];
  const float hs = wf[1024];                      // uniform -> s_load

  const float4 ctr = xq[point];
  const float q = lrelu(fmaf(w0.x, ctr.x, fmaf(w0.y, ctr.y, fmaf(w0.z, ctr.z, w0.w))));
  // k-invariant part of z: wv4*cx + wv5*cy + wv6*cz + hv
  const float cterm = fmaf(w2.x, ctr.x, fmaf(w2.y, ctr.y, fmaf(w2.z, ctr.z, w3.z)));
  // k-invariant part of the score sum: Sigma_c wss_c*q_c + hs
  const float base = wave64_sum(w3.w * q) + hs;

  // Phase 1: prefetch neighbor indices (wave-uniform -> s_loads, batched)
  const int* ip = idx + point * KNN;
  int jn[KNN];
#pragma unroll
  for (int k = 0; k < KNN; ++k) jn[k] = ip[k];

  // Phase 2: all 20 v[k] (loads pipeline; pure fma after)
  float v[KNN];
#pragma unroll
  for (int k = 0; k < KNN; ++k) {
    const float4 nb = xq[(b << 10) + jn[k]];
    const float d0 = nb.x - ctr.x, d1 = nb.y - ctr.y, d2 = nb.z - ctr.z;
    const float ded = fmaf(d0, d0, fmaf(d1, d1, d2 * d2));
    const float z = fmaf(w1.x, ded, fmaf(w1.y, d0, fmaf(w1.z, d1, fmaf(w1.w, d2,
                    fmaf(w2.w, nb.x, fmaf(w3.x, nb.y, fmaf(w3.y, nb.z, cterm)))))));
    v[k] = lrelu(z);
  }

  // Phase 3: 20 independent cross-lane reductions (DPP, VALU-only)
  float s[KNN];
#pragma unroll
  for (int k = 0; k < KNN; ++k) s[k] = lrelu(wave64_sum(w3.w * v[k]) + base);

  // Phase 4: softmax over k; unnormalized accumulate, single divide
  float m = s[0];
#pragma unroll
  for (int k = 1; k < KNN; ++k) m = fmaxf(m, s[k]);
  const float nm = -m * 1.44269504f;
  float den = 0.f, agg = 0.f;
#pragma unroll
  for (int k = 0; k < KNN; ++k) {
    const float e = exp2f(fmaf(s[k], 1.44269504f, nm));
    den += e;
    agg = fmaf(v[k], e, agg);
  }
  agg_out[(point << 6) + c] = agg * (1.0f / den);  // [point][c] -> coalesced
}

// ---------------- K3: conv2 (64x64) + BN + ReLU (thread per point, W2 via SMEM) ----------------
__global__ __launch_bounds__(256) void conv2_kernel(const float* __restrict__ agg,
                                                    const float* __restrict__ W2,
                                                    const float* __restrict__ b2,
                                                    const float* __restrict__ bnc2,
                                                    float* __restrict__ out) {
  const int t = blockIdx.x * 256 + threadIdx.x;  // t = b*1024 + n
  const float4* a4 = (const float4*)(agg + (t << 6));
  float acc[64];
#pragma unroll
  for (int o = 0; o < 64; ++o) acc[o] = 0.f;
#pragma unroll
  for (int cq = 0; cq < 16; ++cq) {
    const float4 a = a4[cq];
#pragma unroll
    for (int o = 0; o < 64; ++o) {
      const float* w = W2 + (o << 6) + (cq << 2);  // threadIdx-independent -> s_load
      acc[o] = fmaf(w[0], a.x, fmaf(w[1], a.y, fmaf(w[2], a.z, fmaf(w[3], a.w, acc[o]))));
    }
  }
  const int b = t >> 10, n = t & 1023;
  float* op = out + (b << 16) + n;
#pragma unroll
  for (int o = 0; o < 64; ++o) {
    const float sc = bnc2[o] / sqrtf(bnc2[192 + o] + EPSBN);
    const float z = acc[o] + b2[o];
    op[o << 10] = fmaxf(fmaf(z - bnc2[128 + o], sc, bnc2[64 + o]), 0.f);
  }
}

extern "C" void kernel_launch(void* const* d_in, const int* in_sizes, int n_in,
                              void* d_out, int out_size, void* d_ws, size_t ws_size,
                              hipStream_t stream) {
  const float* x    = (const float*)d_in[0];
  const float* Wk   = (const float*)d_in[1];
  const float* Wv   = (const float*)d_in[2];
  const float* Ws   = (const float*)d_in[3];
  const float* W2   = (const float*)d_in[4];
  const float* b2   = (const float*)d_in[5];
  const float* bnk  = (const float*)d_in[6];
  const float* bnv  = (const float*)d_in[7];
  const float* bns  = (const float*)d_in[8];
  const float* bnc2 = (const float*)d_in[9];

  // ws layout: xq (1 MB) | idx (5 MB) | agg (16 MB)
  float4* xq = (float4*)d_ws;
  int* idx   = (int*)((char*)d_ws + (1 << 20));
  float* agg = (float*)((char*)d_ws + 6291456);
  float* out = (float*)d_out;
  // Folded-weight scratch (4.1 KB) lives at the START of d_out: lab reads it, then
  // conv2 overwrites every element of d_out (stream-serialized) -> race-free.
  float* wf = (float*)d_out;

  prep_kernel<<<257, 256, 0, stream>>>(x, xq, Wk, Wv, Ws, bnk, bnv, bns, wf);
  knn_kernel<<<16384, 256, 0, stream>>>(xq, idx);
  lab_kernel<<<16384, 256, 0, stream>>>(xq, idx, wf, agg);
  conv2_kernel<<<256, 256, 0, stream>>>(agg, W2, b2, bnc2, out);
}

// Round 7
// 166.001 us; speedup vs baseline: 1.7955x; 1.0690x over previous
//
#include <hip/hip_runtime.h>

#define KNN 20
#define EPSBN 1e-5f

__device__ __forceinline__ float lrelu(float z) { return fmaxf(z, 0.2f * z); }

__device__ __forceinline__ int mbcnt64(unsigned long long m) {
  return __builtin_amdgcn_mbcnt_hi((unsigned)(m >> 32),
                                   __builtin_amdgcn_mbcnt_lo((unsigned)m, 0));
}

// Full-wave (64-lane) float sum via DPP (VALU pipe, no LDS). Result broadcast via
// readlane -> SGPR. Proven in R2-R6.
__device__ __forceinline__ float wave64_sum(float x) {
#define DPP_ADD(ctrl)                                                                   \
  {                                                                                     \
    int _t = __builtin_amdgcn_update_dpp(0, __float_as_int(x), (ctrl), 0xF, 0xF, true); \
    x += __int_as_float(_t);                                                            \
  }
  DPP_ADD(0x111)  // row_shr:1
  DPP_ADD(0x112)  // row_shr:2
  DPP_ADD(0x114)  // row_shr:4
  DPP_ADD(0x118)  // row_shr:8
  DPP_ADD(0x142)  // row_bcast15
  DPP_ADD(0x143)  // row_bcast31 -> lane63 = total
#undef DPP_ADD
  return __int_as_float(__builtin_amdgcn_readlane(__float_as_int(x), 63));
}

// One bitonic stage: exchange with lane^(1<<LJ), keep min/max per standard network.
template <int LK, int LJ>
__device__ __forceinline__ void bstage(unsigned& x, const int* db, int addr32) {
  unsigned p;
  if constexpr (LJ == 5)
    p = (unsigned)__builtin_amdgcn_ds_bpermute(addr32, (int)x);
  else
    p = (unsigned)__builtin_amdgcn_ds_swizzle((int)x, ((1 << LJ) << 10) | 0x1F);
  const unsigned mn = min(x, p), mx = max(x, p);
  x = ((db[LK] ^ db[LJ]) == 0) ? mn : mx;
}

// Full cross-lane bitonic sort of 64 values (one per lane), ascending by lane.
__device__ __forceinline__ unsigned bsort64(unsigned x, const int* db, int addr32) {
  bstage<1, 0>(x, db, addr32);
  bstage<2, 1>(x, db, addr32); bstage<2, 0>(x, db, addr32);
  bstage<3, 2>(x, db, addr32); bstage<3, 1>(x, db, addr32); bstage<3, 0>(x, db, addr32);
  bstage<4, 3>(x, db, addr32); bstage<4, 2>(x, db, addr32); bstage<4, 1>(x, db, addr32);
  bstage<4, 0>(x, db, addr32);
  bstage<5, 4>(x, db, addr32); bstage<5, 3>(x, db, addr32); bstage<5, 2>(x, db, addr32);
  bstage<5, 1>(x, db, addr32); bstage<5, 0>(x, db, addr32);
  bstage<6, 5>(x, db, addr32); bstage<6, 4>(x, db, addr32); bstage<6, 3>(x, db, addr32);
  bstage<6, 2>(x, db, addr32); bstage<6, 1>(x, db, addr32); bstage<6, 0>(x, db, addr32);
  return x;
}

// ---------------- K0: pack points + fold BN/LAB weights (block 256) ----------------
// wf per channel c (16 floats): {wk0,wk1,wk2,hk | wv_ded, wd0,wd1,wd2 | wc0,wc1,wc2,hv |
// wss, -, -, -}; wf[1024] = hs.  Uses nbr = ctr + diff:
// Wv.feat = wv0*ded + Sum (wv[1+i]+wv[7+i])*d_i + Sum (wv[4+i]+wv[7+i])*c_i
__global__ __launch_bounds__(256) void prep_kernel(const float* __restrict__ x,
                                                   float4* __restrict__ xq,
                                                   const float* __restrict__ Wk,
                                                   const float* __restrict__ Wv,
                                                   const float* __restrict__ Ws,
                                                   const float* __restrict__ bnk,
                                                   const float* __restrict__ bnv,
                                                   const float* __restrict__ bns,
                                                   float* __restrict__ wf) {
  if (blockIdx.x == 256) {
    const int c = threadIdx.x;
    if (c < 64) {
      const float sk = bnk[c] / sqrtf(bnk[192 + c] + EPSBN);
      const float hk = bnk[64 + c] - bnk[128 + c] * sk;
      const float sv = bnv[c] / sqrtf(bnv[192 + c] + EPSBN);
      const float hv = bnv[64 + c] - bnv[128 + c] * sv;
      const float ss = bns[0] / sqrtf(bns[3] + EPSBN);
      float* r = wf + (c << 4);
      r[0] = Wk[c * 3 + 0] * sk; r[1] = Wk[c * 3 + 1] * sk; r[2] = Wk[c * 3 + 2] * sk;
      r[3] = hk;
      r[4] = Wv[c * 10 + 0] * sv;
      r[5] = (Wv[c * 10 + 1] + Wv[c * 10 + 7]) * sv;
      r[6] = (Wv[c * 10 + 2] + Wv[c * 10 + 8]) * sv;
      r[7] = (Wv[c * 10 + 3] + Wv[c * 10 + 9]) * sv;
      r[8] = (Wv[c * 10 + 4] + Wv[c * 10 + 7]) * sv;
      r[9] = (Wv[c * 10 + 5] + Wv[c * 10 + 8]) * sv;
      r[10] = (Wv[c * 10 + 6] + Wv[c * 10 + 9]) * sv;
      r[11] = hv;
      r[12] = Ws[c] * ss;
      if (c == 0) wf[1024] = bns[1] - bns[2] * ss;  // hs
    }
    return;
  }
  const int t = blockIdx.x * 256 + threadIdx.x;  // t = b*1024 + n
  const int b = t >> 10, n = t & 1023;
  const float* xb = x + b * 3072;
  const float x0 = xb[n], x1 = xb[1024 + n], x2 = xb[2048 + n];
  float4 p;
  p.x = x0; p.y = x1; p.z = x2;
  p.w = x0 * x0 + x1 * x1 + x2 * x2;
  xq[t] = p;
}

// ---------------- K1: kNN top-20 SET, pop-free (one wave per point) ----------------
// Byte-identical to the R5/R6-proven kernel.
__global__ __launch_bounds__(256) void knn_kernel(const float4* __restrict__ xq,
                                                  int* __restrict__ idx_out) {
  __shared__ unsigned comp[4][64];
  const int lane = threadIdx.x & 63;
  const int w = threadIdx.x >> 6;
  const int point = blockIdx.x * 4 + w;
  const int b = point >> 10;
  const int iself = point & 1023;
  const float4* xb = xq + (b << 10);
  const float4 ci = xq[point];

  unsigned u[16];
#pragma unroll
  for (int r = 0; r < 16; ++r) {
    const int j = (r << 6) + lane;
    const float4 p = xb[j];
    const float dot = ci.x * p.x + ci.y * p.y + ci.z * p.z;
    const float pd = 2.0f * dot - ci.w - p.w;
    const unsigned ub = __float_as_uint(pd) ^ 0x80000000u;
    u[r] = (j == iself) ? 0u : ub;
  }

  int db[7];
#pragma unroll
  for (int a = 0; a < 6; ++a) db[a] = (lane >> a) & 1;
  db[6] = 0;
  const int addr32 = (lane ^ 32) << 2;

  unsigned lm = u[0];
#pragma unroll
  for (int r = 1; r < 16; ++r) lm = min(lm, u[r]);

  const unsigned sm = bsort64(lm, db, addr32);
  const unsigned tau = (unsigned)__builtin_amdgcn_readlane((int)sm, 19);

  unsigned* cw = comp[w];
  cw[lane] = 0xFFFFFFFFu;
  __syncthreads();
  int base = 0;
#pragma unroll
  for (int r = 0; r < 16; ++r) {
    const bool sel = (u[r] <= tau);
    const unsigned long long m = __ballot(sel);
    const int pos = base + mbcnt64(m);
    if (sel && pos < 64) cw[pos] = u[r];
    base += __popcll(m);
  }
  __syncthreads();
  unsigned sv = cw[lane];

  unsigned T;
  if (base <= 64) {
    sv = bsort64(sv, db, addr32);
    T = (unsigned)__builtin_amdgcn_readlane((int)sv, 19);
  } else {
    T = 0u;
    for (int bit = 30; bit >= 0; --bit) {
      const unsigned cand = T | (1u << bit);
      int cnt = 0;
#pragma unroll
      for (int r = 0; r < 16; ++r) cnt += __popcll(__ballot(u[r] < cand));
      if (cnt <= 19) T = cand;
    }
  }

  int* op = idx_out + point * KNN;
  int nbase = 0;
#pragma unroll
  for (int r = 0; r < 16; ++r) {
    const bool sel = (u[r] < T);
    const unsigned long long m = __ballot(sel);
    const int pos = nbase + mbcnt64(m);
    if (sel) op[pos] = (r << 6) + lane;
    nbase += __popcll(m);
  }
  for (int r = 0; r < 16 && nbase < KNN; ++r) {
    const bool sel = (u[r] == T);
    const unsigned long long m = __ballot(sel);
    const int pos = nbase + mbcnt64(m);
    if (sel && pos < KNN) op[pos] = (r << 6) + lane;
    nbase += __popcll(m);
  }
}

// ---------------- K2: LAB attention v3 (one wave per point, lane = channel) ----------------
// Score reduction via per-wave LDS transpose instead of 20 DPP ladders:
// write wss_c*v_ck to [c][k] (pad 21), 3 lane-groups of 20 serially sum ~22 rows each
// (LDS pipe), 2 bpermute combine, 20 readlane broadcast. Same-wave LDS ops are ordered;
// tile is wave-private -> no barrier.
__global__ __launch_bounds__(256) void lab_kernel(const float4* __restrict__ xq,
                                                  const int* __restrict__ idx,
                                                  const float* __restrict__ wf,
                                                  float* __restrict__ agg_out) {
  __shared__ float tld[4][64][21];
  const int lane = threadIdx.x & 63;
  const int w = threadIdx.x >> 6;
  int point = (blockIdx.x << 2) + w;
  point = __builtin_amdgcn_readfirstlane(point);  // wave-uniform -> scalar loads
  const int b = point >> 10;
  const int c = lane;

  const float4* wfc = (const float4*)(wf + (c << 4));
  const float4 w0 = wfc[0];   // wk0,wk1,wk2,hk
  const float4 w1 = wfc[1];   // wv_ded, wd0, wd1, wd2
  const float4 w2 = wfc[2];   // wc0, wc1, wc2, hv
  const float wss = wf[(c << 4) + 12];
  const float hs = wf[1024];                      // uniform -> s_load

  const float4 ctr = xq[point];
  const float q = lrelu(fmaf(w0.x, ctr.x, fmaf(w0.y, ctr.y, fmaf(w0.z, ctr.z, w0.w))));
  // k-invariant: wc.ctr + hv (covers both the ctr and the nbr=ctr+d expansion)
  const float cterm = fmaf(w2.x, ctr.x, fmaf(w2.y, ctr.y, fmaf(w2.z, ctr.z, w2.w)));
  // k-invariant score part: Sigma_c wss_c*q_c + hs
  const float base = wave64_sum(wss * q) + hs;

  // Phase 1: prefetch neighbor indices (wave-uniform -> s_loads)
  const int* ip = idx + point * KNN;
  int jn[KNN];
#pragma unroll
  for (int k = 0; k < KNN; ++k) jn[k] = ip[k];

  // Phase 2: all 20 v[k] (4-fma folded form)
  float v[KNN];
#pragma unroll
  for (int k = 0; k < KNN; ++k) {
    const float4 nb = xq[(b << 10) + jn[k]];
    const float d0 = nb.x - ctr.x, d1 = nb.y - ctr.y, d2 = nb.z - ctr.z;
    const float ded = fmaf(d0, d0, fmaf(d1, d1, d2 * d2));
    const float z = fmaf(w1.x, ded, fmaf(w1.y, d0, fmaf(w1.z, d1, fmaf(w1.w, d2, cterm))));
    v[k] = lrelu(z);
  }

  // Phase 3: transpose reduction. Lane c writes its 20 contributions to row c.
  float* trow = &tld[w][c][0];
#pragma unroll
  for (int k = 0; k < KNN; ++k) trow[k] = wss * v[k];
  // lane -> (k-column kk, c-group g): g0 sums c 0..21, g1 22..42, g2 43..63.
  const int g = lane / 20;                         // 3 for lanes 60..63 (results unused)
  const int kk = lane - g * 20;
  const int c0 = (g == 0) ? 0 : ((g == 1) ? 22 : 43);
  const int cnt = (g == 0) ? 22 : 21;
  float part = 0.f;
#pragma unroll
  for (int i = 0; i < 22; ++i)
    if (i < cnt) part += tld[w][c0 + i][kk];
  const float p1 = __int_as_float(
      __builtin_amdgcn_ds_bpermute((kk + 20) << 2, __float_as_int(part)));
  const float p2 = __int_as_float(
      __builtin_amdgcn_ds_bpermute((kk + 40) << 2, __float_as_int(part)));
  const float sfull = lrelu(part + p1 + p2 + base);  // valid in lanes 0..19

  float sk_[KNN];
#pragma unroll
  for (int k = 0; k < KNN; ++k)
    sk_[k] = __int_as_float(__builtin_amdgcn_readlane(__float_as_int(sfull), k));

  // Phase 4: softmax over k; unnormalized accumulate, single divide
  float m = sk_[0];
#pragma unroll
  for (int k = 1; k < KNN; ++k) m = fmaxf(m, sk_[k]);
  const float nm = -m * 1.44269504f;
  float den = 0.f, agg = 0.f;
#pragma unroll
  for (int k = 0; k < KNN; ++k) {
    const float e = exp2f(fmaf(sk_[k], 1.44269504f, nm));
    den += e;
    agg = fmaf(v[k], e, agg);
  }
  agg_out[(point << 6) + c] = agg * (1.0f / den);  // [point][c] -> coalesced
}

// ---------------- K3: conv2 (64x64) + BN + ReLU (byte-identical, proven) ----------------
__global__ __launch_bounds__(256) void conv2_kernel(const float* __restrict__ agg,
                                                    const float* __restrict__ W2,
                                                    const float* __restrict__ b2,
                                                    const float* __restrict__ bnc2,
                                                    float* __restrict__ out) {
  const int t = blockIdx.x * 256 + threadIdx.x;  // t = b*1024 + n
  const float4* a4 = (const float4*)(agg + (t << 6));
  float acc[64];
#pragma unroll
  for (int o = 0; o < 64; ++o) acc[o] = 0.f;
#pragma unroll
  for (int cq = 0; cq < 16; ++cq) {
    const float4 a = a4[cq];
#pragma unroll
    for (int o = 0; o < 64; ++o) {
      const float* w = W2 + (o << 6) + (cq << 2);
      acc[o] = fmaf(w[0], a.x, fmaf(w[1], a.y, fmaf(w[2], a.z, fmaf(w[3], a.w, acc[o]))));
    }
  }
  const int b = t >> 10, n = t & 1023;
  float* op = out + (b << 16) + n;
#pragma unroll
  for (int o = 0; o < 64; ++o) {
    const float sc = bnc2[o] / sqrtf(bnc2[192 + o] + EPSBN);
    const float z = acc[o] + b2[o];
    op[o << 10] = fmaxf(fmaf(z - bnc2[128 + o], sc, bnc2[64 + o]), 0.f);
  }
}

extern "C" void kernel_launch(void* const* d_in, const int* in_sizes, int n_in,
                              void* d_out, int out_size, void* d_ws, size_t ws_size,
                              hipStream_t stream) {
  const float* x    = (const float*)d_in[0];
  const float* Wk   = (const float*)d_in[1];
  const float* Wv   = (const float*)d_in[2];
  const float* Ws   = (const float*)d_in[3];
  const float* W2   = (const float*)d_in[4];
  const float* b2   = (const float*)d_in[5];
  const float* bnk  = (const float*)d_in[6];
  const float* bnv  = (const float*)d_in[7];
  const float* bns  = (const float*)d_in[8];
  const float* bnc2 = (const float*)d_in[9];

  // ws layout: xq (1 MB) | idx (5.24 MB) | agg (16 MB)
  float4* xq = (float4*)d_ws;
  int* idx   = (int*)((char*)d_ws + (1 << 20));
  float* agg = (float*)((char*)d_ws + 6291456);
  float* out = (float*)d_out;
  // Folded-weight scratch (4.1 KB) at the START of d_out: lab reads it, then conv2
  // overwrites every element of d_out (stream-serialized) -> race-free.
  float* wf = (float*)d_out;

  prep_kernel<<<257, 256, 0, stream>>>(x, xq, Wk, Wv, Ws, bnk, bnv, bns, wf);
  knn_kernel<<<16384, 256, 0, stream>>>(xq, idx);
  lab_kernel<<<16384, 256, 0, stream>>>(xq, idx, wf, agg);
  conv2_kernel<<<256, 256, 0, stream>>>(agg, W2, b2, bnc2, out);
}

// Round 8
// 148.446 us; speedup vs baseline: 2.0078x; 1.1183x over previous
//
#include <hip/hip_runtime.h>

#define KNN 20
#define EPSBN 1e-5f

__device__ __forceinline__ float lrelu(float z) { return fmaxf(z, 0.2f * z); }

__device__ __forceinline__ int mbcnt64(unsigned long long m) {
  return __builtin_amdgcn_mbcnt_hi((unsigned)(m >> 32),
                                   __builtin_amdgcn_mbcnt_lo((unsigned)m, 0));
}

// Full-wave (64-lane) float sum via DPP (VALU pipe, no LDS). Proven R2-R7.
__device__ __forceinline__ float wave64_sum(float x) {
#define DPP_ADD(ctrl)                                                                   \
  {                                                                                     \
    int _t = __builtin_amdgcn_update_dpp(0, __float_as_int(x), (ctrl), 0xF, 0xF, true); \
    x += __int_as_float(_t);                                                            \
  }
  DPP_ADD(0x111)  // row_shr:1
  DPP_ADD(0x112)  // row_shr:2
  DPP_ADD(0x114)  // row_shr:4
  DPP_ADD(0x118)  // row_shr:8
  DPP_ADD(0x142)  // row_bcast15
  DPP_ADD(0x143)  // row_bcast31 -> lane63 = total
#undef DPP_ADD
  return __int_as_float(__builtin_amdgcn_readlane(__float_as_int(x), 63));
}

// One bitonic stage: exchange with lane^(1<<LJ), keep min/max per standard network.
template <int LK, int LJ>
__device__ __forceinline__ void bstage(unsigned& x, const int* db, int addr32) {
  unsigned p;
  if constexpr (LJ == 5)
    p = (unsigned)__builtin_amdgcn_ds_bpermute(addr32, (int)x);
  else
    p = (unsigned)__builtin_amdgcn_ds_swizzle((int)x, ((1 << LJ) << 10) | 0x1F);
  const unsigned mn = min(x, p), mx = max(x, p);
  x = ((db[LK] ^ db[LJ]) == 0) ? mn : mx;
}

// Full cross-lane bitonic sort of 64 values (one per lane), ascending by lane.
__device__ __forceinline__ unsigned bsort64(unsigned x, const int* db, int addr32) {
  bstage<1, 0>(x, db, addr32);
  bstage<2, 1>(x, db, addr32); bstage<2, 0>(x, db, addr32);
  bstage<3, 2>(x, db, addr32); bstage<3, 1>(x, db, addr32); bstage<3, 0>(x, db, addr32);
  bstage<4, 3>(x, db, addr32); bstage<4, 2>(x, db, addr32); bstage<4, 1>(x, db, addr32);
  bstage<4, 0>(x, db, addr32);
  bstage<5, 4>(x, db, addr32); bstage<5, 3>(x, db, addr32); bstage<5, 2>(x, db, addr32);
  bstage<5, 1>(x, db, addr32); bstage<5, 0>(x, db, addr32);
  bstage<6, 5>(x, db, addr32); bstage<6, 4>(x, db, addr32); bstage<6, 3>(x, db, addr32);
  bstage<6, 2>(x, db, addr32); bstage<6, 1>(x, db, addr32); bstage<6, 0>(x, db, addr32);
  return x;
}

// ---------------- K0: pack points + fold BN/LAB weights (byte-identical to R7) ----------------
__global__ __launch_bounds__(256) void prep_kernel(const float* __restrict__ x,
                                                   float4* __restrict__ xq,
                                                   const float* __restrict__ Wk,
                                                   const float* __restrict__ Wv,
                                                   const float* __restrict__ Ws,
                                                   const float* __restrict__ bnk,
                                                   const float* __restrict__ bnv,
                                                   const float* __restrict__ bns,
                                                   float* __restrict__ wf) {
  if (blockIdx.x == 256) {
    const int c = threadIdx.x;
    if (c < 64) {
      const float sk = bnk[c] / sqrtf(bnk[192 + c] + EPSBN);
      const float hk = bnk[64 + c] - bnk[128 + c] * sk;
      const float sv = bnv[c] / sqrtf(bnv[192 + c] + EPSBN);
      const float hv = bnv[64 + c] - bnv[128 + c] * sv;
      const float ss = bns[0] / sqrtf(bns[3] + EPSBN);
      float* r = wf + (c << 4);
      r[0] = Wk[c * 3 + 0] * sk; r[1] = Wk[c * 3 + 1] * sk; r[2] = Wk[c * 3 + 2] * sk;
      r[3] = hk;
      r[4] = Wv[c * 10 + 0] * sv;
      r[5] = (Wv[c * 10 + 1] + Wv[c * 10 + 7]) * sv;
      r[6] = (Wv[c * 10 + 2] + Wv[c * 10 + 8]) * sv;
      r[7] = (Wv[c * 10 + 3] + Wv[c * 10 + 9]) * sv;
      r[8] = (Wv[c * 10 + 4] + Wv[c * 10 + 7]) * sv;
      r[9] = (Wv[c * 10 + 5] + Wv[c * 10 + 8]) * sv;
      r[10] = (Wv[c * 10 + 6] + Wv[c * 10 + 9]) * sv;
      r[11] = hv;
      r[12] = Ws[c] * ss;
      if (c == 0) wf[1024] = bns[1] - bns[2] * ss;  // hs
    }
    return;
  }
  const int t = blockIdx.x * 256 + threadIdx.x;  // t = b*1024 + n
  const int b = t >> 10, n = t & 1023;
  const float* xb = x + b * 3072;
  const float x0 = xb[n], x1 = xb[1024 + n], x2 = xb[2048 + n];
  float4 p;
  p.x = x0; p.y = x1; p.z = x2;
  p.w = x0 * x0 + x1 * x1 + x2 * x2;
  xq[t] = p;
}

// ---------------- K1: FUSED kNN + LAB attention (one wave per point) ----------------
// Selection = R5/R7-proven path (tau from sorted lane-mins -> compact survivors ->
// sort -> exact T -> two compaction passes, top_k tie semantics), retargeted to a
// wave-private LDS slot instead of global idx. No __syncthreads: comp/tld tiles are
// wave-private and same-wave LDS ops are ordered. Then the R7-proven LAB math runs
// in the same wave (lane = channel), indices read back via readlane -> s_load gathers.
__global__ __launch_bounds__(256) void point_kernel(const float4* __restrict__ xq,
                                                    const float* __restrict__ wf,
                                                    float* __restrict__ agg_out) {
  __shared__ float tld[4][64][21];
  __shared__ unsigned comp[4][64];
  const int lane = threadIdx.x & 63;
  const int w = threadIdx.x >> 6;
  const int point = __builtin_amdgcn_readfirstlane(blockIdx.x * 4 + w);  // wave-uniform
  const int b = point >> 10;
  const int iself = point & 1023;
  const float4* xb = xq + (b << 10);

  // Lab weights issued early: VMEM latency hides under the distance phase.
  const int c = lane;
  const float4* wfc = (const float4*)(wf + (c << 4));
  const float4 w0 = wfc[0];   // wk0,wk1,wk2,hk
  const float4 w1 = wfc[1];   // wv_ded, wd0, wd1, wd2
  const float4 w2 = wfc[2];   // wc0, wc1, wc2, hv
  const float wss = wf[(c << 4) + 12];
  const float hs = wf[1024];
  const float4 ci = xq[point];                         // uniform -> s_load

  // ---- phase A: distances (bit-identical to R2-R7) ----
  unsigned u[16];
#pragma unroll
  for (int r = 0; r < 16; ++r) {
    const int j = (r << 6) + lane;
    const float4 p = xb[j];
    const float dot = ci.x * p.x + ci.y * p.y + ci.z * p.z;
    const float pd = 2.0f * dot - ci.w - p.w;
    const unsigned ub = __float_as_uint(pd) ^ 0x80000000u;
    u[r] = (j == iself) ? 0u : ub;
  }

  int db[7];
#pragma unroll
  for (int a = 0; a < 6; ++a) db[a] = (lane >> a) & 1;
  db[6] = 0;
  const int addr32 = (lane ^ 32) << 2;

  unsigned lm = u[0];
#pragma unroll
  for (int r = 1; r < 16; ++r) lm = min(lm, u[r]);

  const unsigned sm = bsort64(lm, db, addr32);
  const unsigned tau = (unsigned)__builtin_amdgcn_readlane((int)sm, 19);

  unsigned* cw = comp[w];
  cw[lane] = 0xFFFFFFFFu;
  int base = 0;
#pragma unroll
  for (int r = 0; r < 16; ++r) {
    const bool sel = (u[r] <= tau);
    const unsigned long long m = __ballot(sel);
    const int pos = base + mbcnt64(m);
    if (sel && pos < 64) cw[pos] = u[r];
    base += __popcll(m);
  }
  unsigned sv = cw[lane];

  unsigned T;
  if (base <= 64) {                              // always, in practice
    sv = bsort64(sv, db, addr32);
    T = (unsigned)__builtin_amdgcn_readlane((int)sv, 19);
  } else {
    T = 0u;                                      // proven R3 bisection fallback
    for (int bit = 30; bit >= 0; --bit) {
      const unsigned cand = T | (1u << bit);
      int cnt = 0;
#pragma unroll
      for (int r = 0; r < 16; ++r) cnt += __popcll(__ballot(u[r] < cand));
      if (cnt <= 19) T = cand;
    }
  }

  // ---- phase B: collect winner indices into wave-private LDS (same tie semantics) ----
  int nbase = 0;
#pragma unroll
  for (int r = 0; r < 16; ++r) {
    const bool sel = (u[r] < T);
    const unsigned long long m = __ballot(sel);
    const int pos = nbase + mbcnt64(m);
    if (sel) cw[pos] = (unsigned)((r << 6) + lane);
    nbase += __popcll(m);
  }
  for (int r = 0; r < 16 && nbase < KNN; ++r) {
    const bool sel = (u[r] == T);
    const unsigned long long m = __ballot(sel);
    const int pos = nbase + mbcnt64(m);
    if (sel && pos < KNN) cw[pos] = (unsigned)((r << 6) + lane);
    nbase += __popcll(m);
  }
  const int jsel = (int)cw[lane];                // lane k holds winner k (k<20)

  // ---- phase C: LAB attention (R7-proven math) ----
  const float q = lrelu(fmaf(w0.x, ci.x, fmaf(w0.y, ci.y, fmaf(w0.z, ci.z, w0.w))));
  const float cterm = fmaf(w2.x, ci.x, fmaf(w2.y, ci.y, fmaf(w2.z, ci.z, w2.w)));
  const float sbase = wave64_sum(wss * q) + hs;

  float v[KNN];
#pragma unroll
  for (int k = 0; k < KNN; ++k) {
    const int jk = __builtin_amdgcn_readlane(jsel, k);   // SGPR -> uniform gather
    const float4 nb = xb[jk];
    const float d0 = nb.x - ci.x, d1 = nb.y - ci.y, d2 = nb.z - ci.z;
    const float ded = fmaf(d0, d0, fmaf(d1, d1, d2 * d2));
    const float z = fmaf(w1.x, ded, fmaf(w1.y, d0, fmaf(w1.z, d1, fmaf(w1.w, d2, cterm))));
    v[k] = lrelu(z);
  }

  // Transpose reduction over channels via wave-private LDS tile (R7-proven).
  float* trow = &tld[w][c][0];
#pragma unroll
  for (int k = 0; k < KNN; ++k) trow[k] = wss * v[k];
  const int g = lane / 20;                       // 3 for lanes 60..63 (unused results)
  const int kk = lane - g * 20;
  const int c0 = (g == 0) ? 0 : ((g == 1) ? 22 : 43);
  const int cnt = (g == 0) ? 22 : 21;
  float part = 0.f;
#pragma unroll
  for (int i = 0; i < 22; ++i)
    if (i < cnt) part += tld[w][c0 + i][kk];
  const float p1 = __int_as_float(
      __builtin_amdgcn_ds_bpermute((kk + 20) << 2, __float_as_int(part)));
  const float p2 = __int_as_float(
      __builtin_amdgcn_ds_bpermute((kk + 40) << 2, __float_as_int(part)));
  const float sfull = lrelu(part + p1 + p2 + sbase);  // valid in lanes 0..19

  float sk_[KNN];
#pragma unroll
  for (int k = 0; k < KNN; ++k)
    sk_[k] = __int_as_float(__builtin_amdgcn_readlane(__float_as_int(sfull), k));

  float m = sk_[0];
#pragma unroll
  for (int k = 1; k < KNN; ++k) m = fmaxf(m, sk_[k]);
  const float nm = -m * 1.44269504f;
  float den = 0.f, agg = 0.f;
#pragma unroll
  for (int k = 0; k < KNN; ++k) {
    const float e = exp2f(fmaf(sk_[k], 1.44269504f, nm));
    den += e;
    agg = fmaf(v[k], e, agg);
  }
  agg_out[(point << 6) + c] = agg * (1.0f / den);  // [point][c] -> coalesced
}

// ---------------- K3: conv2 (64x64) + BN + ReLU (byte-identical, proven) ----------------
__global__ __launch_bounds__(256) void conv2_kernel(const float* __restrict__ agg,
                                                    const float* __restrict__ W2,
                                                    const float* __restrict__ b2,
                                                    const float* __restrict__ bnc2,
                                                    float* __restrict__ out) {
  const int t = blockIdx.x * 256 + threadIdx.x;  // t = b*1024 + n
  const float4* a4 = (const float4*)(agg + (t << 6));
  float acc[64];
#pragma unroll
  for (int o = 0; o < 64; ++o) acc[o] = 0.f;
#pragma unroll
  for (int cq = 0; cq < 16; ++cq) {
    const float4 a = a4[cq];
#pragma unroll
    for (int o = 0; o < 64; ++o) {
      const float* w = W2 + (o << 6) + (cq << 2);
      acc[o] = fmaf(w[0], a.x, fmaf(w[1], a.y, fmaf(w[2], a.z, fmaf(w[3], a.w, acc[o]))));
    }
  }
  const int b = t >> 10, n = t & 1023;
  float* op = out + (b << 16) + n;
#pragma unroll
  for (int o = 0; o < 64; ++o) {
    const float sc = bnc2[o] / sqrtf(bnc2[192 + o] + EPSBN);
    const float z = acc[o] + b2[o];
    op[o << 10] = fmaxf(fmaf(z - bnc2[128 + o], sc, bnc2[64 + o]), 0.f);
  }
}

extern "C" void kernel_launch(void* const* d_in, const int* in_sizes, int n_in,
                              void* d_out, int out_size, void* d_ws, size_t ws_size,
                              hipStream_t stream) {
  const float* x    = (const float*)d_in[0];
  const float* Wk   = (const float*)d_in[1];
  const float* Wv   = (const float*)d_in[2];
  const float* Ws   = (const float*)d_in[3];
  const float* W2   = (const float*)d_in[4];
  const float* b2   = (const float*)d_in[5];
  const float* bnk  = (const float*)d_in[6];
  const float* bnv  = (const float*)d_in[7];
  const float* bns  = (const float*)d_in[8];
  const float* bnc2 = (const float*)d_in[9];

  // ws layout: xq (1 MB) | agg (16 MB). (idx round-trip eliminated by fusion.)
  float4* xq = (float4*)d_ws;
  float* agg = (float*)((char*)d_ws + 6291456);
  float* out = (float*)d_out;
  // Folded-weight scratch (4.1 KB) at the START of d_out: point_kernel reads it, then
  // conv2 overwrites every element of d_out (stream-serialized) -> race-free.
  float* wf = (float*)d_out;

  prep_kernel<<<257, 256, 0, stream>>>(x, xq, Wk, Wv, Ws, bnk, bnv, bns, wf);
  point_kernel<<<16384, 256, 0, stream>>>(xq, wf, agg);
  conv2_kernel<<<256, 256, 0, stream>>>(agg, W2, b2, bnc2, out);
}